// Round 1
// baseline (3890.283 us; speedup 1.0000x reference)
//
#include <hip/hip_runtime.h>
#include <math.h>

#define B_   32
#define SEQ_ 2048
#define DIM_ 512
#define KSEL 128
#define LSTR 132   // LDS row stride (floats), padded to kill power-of-2 conflicts

__device__ __forceinline__ float gelu_exact(float v) {
  return 0.5f * v * (1.0f + erff(v * 0.70710678118654752440f));
}

// ---------------------------------------------------------------- stats ----
// mean/rstd of rows of length 512. grid = rows/4, block = 256 (4 waves, 1 row/wave)
__global__ __launch_bounds__(256) void rowstats512(const float* __restrict__ X,
                                                   float* __restrict__ mean,
                                                   float* __restrict__ rstd) {
  int row = blockIdx.x * 4 + (threadIdx.x >> 6);
  int l = threadIdx.x & 63;
  const float4* p = (const float4*)(X + (size_t)row * 512);
  float4 v0 = p[l * 2], v1 = p[l * 2 + 1];
  float s = v0.x + v0.y + v0.z + v0.w + v1.x + v1.y + v1.z + v1.w;
  float q = v0.x*v0.x + v0.y*v0.y + v0.z*v0.z + v0.w*v0.w
          + v1.x*v1.x + v1.y*v1.y + v1.z*v1.z + v1.w*v1.w;
#pragma unroll
  for (int off = 32; off > 0; off >>= 1) {
    s += __shfl_down(s, off);
    q += __shfl_down(q, off);
  }
  if (l == 0) {
    float m = s * (1.0f / 512.0f);
    float var = q * (1.0f / 512.0f) - m * m;
    mean[row] = m;
    rstd[row] = rsqrtf(var + 1e-5f);
  }
}

// LN2 stats: mean/rstd over s of x_tok[b, s, d].  Pass 1: partial sums.
// grid = B*8 (b = bid>>3, part = bid&7), block = 512 (one thread per d)
__global__ __launch_bounds__(512) void colstats_part(const float* __restrict__ xtok,
                                                     float2* __restrict__ part) {
  int b = blockIdx.x >> 3, pr = blockIdx.x & 7;
  int d = threadIdx.x;
  const float* src = xtok + ((size_t)b * SEQ_ + (size_t)pr * 256) * 512 + d;
  float s = 0.f, q = 0.f;
#pragma unroll 4
  for (int i = 0; i < 256; ++i) {
    float v = src[(size_t)i * 512];
    s += v; q += v * v;
  }
  part[(size_t)blockIdx.x * 512 + d] = make_float2(s, q);
}

// Pass 2: combine 8 partials. grid = 64, block = 256. idx = b*512 + d
__global__ __launch_bounds__(256) void colstats_fin(const float2* __restrict__ part,
                                                    float* __restrict__ mean,
                                                    float* __restrict__ rstd) {
  int idx = blockIdx.x * 256 + threadIdx.x;
  int b = idx >> 9, d = idx & 511;
  float s = 0.f, q = 0.f;
#pragma unroll
  for (int p = 0; p < 8; ++p) {
    float2 v = part[((size_t)(b * 8 + p)) * 512 + d];
    s += v.x; q += v.y;
  }
  float m = s * (1.0f / 2048.0f);
  mean[idx] = m;
  rstd[idx] = rsqrtf(q * (1.0f / 2048.0f) - m * m + 1e-5f);
}

// ------------------------------------------------------------- GEMM core ----
// 128x128 tile, BK=16, 256 threads, each thread: 2x2 blocks of 4x4 outputs.
__device__ __forceinline__ void mm_tile(const float* As, const float* Bs,
                                        int tx, int ty, float acc[2][2][4][4]) {
#pragma unroll
  for (int kk = 0; kk < 16; ++kk) {
    const float* ar = As + kk * LSTR;
    const float* br = Bs + kk * LSTR;
    float4 a0 = *(const float4*)(ar + ty * 4);
    float4 a1 = *(const float4*)(ar + ty * 4 + 64);
    float4 b0 = *(const float4*)(br + tx * 4);
    float4 b1 = *(const float4*)(br + tx * 4 + 64);
    float av[2][4] = {{a0.x, a0.y, a0.z, a0.w}, {a1.x, a1.y, a1.z, a1.w}};
    float bv[2][4] = {{b0.x, b0.y, b0.z, b0.w}, {b1.x, b1.y, b1.z, b1.w}};
#pragma unroll
    for (int mi = 0; mi < 2; ++mi)
#pragma unroll
      for (int i = 0; i < 4; ++i)
#pragma unroll
        for (int ni = 0; ni < 2; ++ni)
#pragma unroll
          for (int j = 0; j < 4; ++j)
            acc[mi][ni][i][j] = fmaf(av[mi][i], bv[ni][j], acc[mi][ni][i][j]);
  }
}

// B tile loader: row-major KxN, vectorized (requires 16B-aligned rows)
__device__ __forceinline__ void load_b_tile(const float* __restrict__ Bm, int ldb,
                                            int k0, int n0, float* Bs, int t) {
  int kr = t >> 4;
  int nc = (t & 15) * 8;
  const float* src = Bm + (size_t)(k0 + kr) * ldb + n0 + nc;
  float4 v0 = *(const float4*)(src);
  float4 v1 = *(const float4*)(src + 4);
  *(float4*)(Bs + kr * LSTR + nc) = v0;
  *(float4*)(Bs + kr * LSTR + nc + 4) = v1;
}

// A tile loader: row-major MxK with layernorm applied on the fly (stats per row,
// gamma/beta per k). Stores transposed As[k][m].
__device__ __forceinline__ void load_a_ln(const float* __restrict__ X, int ldx,
                                          const float* __restrict__ mean,
                                          const float* __restrict__ rstd,
                                          const float* __restrict__ g,
                                          const float* __restrict__ bl,
                                          int m0, int k0, float* As, int t) {
  int rl = t >> 1;
  int cl = (t & 1) * 8;
  int r = m0 + rl, c = k0 + cl;
  float m = mean[r], sd = rstd[r];
  const float* src = X + (size_t)r * ldx + c;
  float4 x0 = *(const float4*)(src);
  float4 x1 = *(const float4*)(src + 4);
  float4 g0 = *(const float4*)(g + c);
  float4 g1 = *(const float4*)(g + c + 4);
  float4 b0 = *(const float4*)(bl + c);
  float4 b1 = *(const float4*)(bl + c + 4);
  float v[8];
  v[0] = (x0.x - m) * sd * g0.x + b0.x;
  v[1] = (x0.y - m) * sd * g0.y + b0.y;
  v[2] = (x0.z - m) * sd * g0.z + b0.z;
  v[3] = (x0.w - m) * sd * g0.w + b0.w;
  v[4] = (x1.x - m) * sd * g1.x + b1.x;
  v[5] = (x1.y - m) * sd * g1.y + b1.y;
  v[6] = (x1.z - m) * sd * g1.z + b1.z;
  v[7] = (x1.w - m) * sd * g1.w + b1.w;
#pragma unroll
  for (int i = 0; i < 8; ++i) As[(cl + i) * LSTR + rl] = v[i];
}

// A tile loader: plain row-major MxK (GZ). Stores transposed.
__device__ __forceinline__ void load_a_plain(const float* __restrict__ A, int lda,
                                             int m0, int k0, float* As, int t) {
  int rl = t >> 1;
  int cl = (t & 1) * 8;
  const float* src = A + (size_t)(m0 + rl) * lda + k0 + cl;
  float4 v0 = *(const float4*)(src);
  float4 v1 = *(const float4*)(src + 4);
  float v[8] = {v0.x, v0.y, v0.z, v0.w, v1.x, v1.y, v1.z, v1.w};
#pragma unroll
  for (int i = 0; i < 8; ++i) As[(cl + i) * LSTR + rl] = v[i];
}

// ------------------------------------------------------------------ G1 ----
// x_tok = gelu(ln1(x) @ W1 + b1).  grid (4, 512)
__global__ __launch_bounds__(256) void g1_kernel(const float* __restrict__ x,
    const float* __restrict__ mean, const float* __restrict__ rstd,
    const float* __restrict__ g1, const float* __restrict__ bl1,
    const float* __restrict__ W1, const float* __restrict__ b1,
    float* __restrict__ xtok) {
  __shared__ float As[16 * LSTR], Bs[16 * LSTR];
  int t = threadIdx.x;
  int m0 = blockIdx.y * 128, n0 = blockIdx.x * 128;
  float acc[2][2][4][4] = {};
  for (int k0 = 0; k0 < 512; k0 += 16) {
    load_a_ln(x, 512, mean, rstd, g1, bl1, m0, k0, As, t);
    load_b_tile(W1, 512, k0, n0, Bs, t);
    __syncthreads();
    mm_tile(As, Bs, t & 15, t >> 4, acc);
    __syncthreads();
  }
  int tx = t & 15, ty = t >> 4;
#pragma unroll
  for (int mi = 0; mi < 2; ++mi)
#pragma unroll
    for (int ni = 0; ni < 2; ++ni) {
      int cb = n0 + ni * 64 + tx * 4;
      float4 bias = *(const float4*)(b1 + cb);
#pragma unroll
      for (int i = 0; i < 4; ++i) {
        int r = m0 + mi * 64 + ty * 4 + i;
        float4 o;
        o.x = gelu_exact(acc[mi][ni][i][0] + bias.x);
        o.y = gelu_exact(acc[mi][ni][i][1] + bias.y);
        o.z = gelu_exact(acc[mi][ni][i][2] + bias.z);
        o.w = gelu_exact(acc[mi][ni][i][3] + bias.w);
        *(float4*)(xtok + (size_t)r * 512 + cb) = o;
      }
    }
}

// ------------------------------------------------------------------ G2 ----
// x_sum[b,s',d] = x_tok[b,s',d] + gelu( ln2(x_tok^T)[d,:] @ W2[:,s'] + b2[s'] )
// grid (16, 4, 32): n-tiles (s'), m-tiles (d), batch
__global__ __launch_bounds__(256) void g2_kernel(const float* __restrict__ xtok,
    const float* __restrict__ mean2, const float* __restrict__ rstd2,
    const float* __restrict__ g2, const float* __restrict__ bl2,
    const float* __restrict__ W2, const float* __restrict__ b2,
    float* __restrict__ xsum) {
  __shared__ float As[16 * LSTR], Bs[16 * LSTR];
  int t = threadIdx.x;
  int b = blockIdx.z;
  int m0 = blockIdx.y * 128, n0 = blockIdx.x * 128;
  float acc[2][2][4][4] = {};
  for (int k0 = 0; k0 < 2048; k0 += 16) {
    {  // A: normalized transpose of x_tok
      int sl = t >> 4;
      int dl = (t & 15) * 8;
      int s = k0 + sl, d = m0 + dl;
      const float* src = xtok + ((size_t)b * SEQ_ + s) * 512 + d;
      float4 x0 = *(const float4*)(src);
      float4 x1 = *(const float4*)(src + 4);
      const float* mp = mean2 + b * 512 + d;
      const float* rp = rstd2 + b * 512 + d;
      float4 mv0 = *(const float4*)(mp), mv1 = *(const float4*)(mp + 4);
      float4 rv0 = *(const float4*)(rp), rv1 = *(const float4*)(rp + 4);
      float gg = g2[s], bb = bl2[s];
      float4 o0, o1;
      o0.x = (x0.x - mv0.x) * rv0.x * gg + bb;
      o0.y = (x0.y - mv0.y) * rv0.y * gg + bb;
      o0.z = (x0.z - mv0.z) * rv0.z * gg + bb;
      o0.w = (x0.w - mv0.w) * rv0.w * gg + bb;
      o1.x = (x1.x - mv1.x) * rv1.x * gg + bb;
      o1.y = (x1.y - mv1.y) * rv1.y * gg + bb;
      o1.z = (x1.z - mv1.z) * rv1.z * gg + bb;
      o1.w = (x1.w - mv1.w) * rv1.w * gg + bb;
      *(float4*)(As + sl * LSTR + dl) = o0;
      *(float4*)(As + sl * LSTR + dl + 4) = o1;
    }
    load_b_tile(W2, 2048, k0, n0, Bs, t);
    __syncthreads();
    mm_tile(As, Bs, t & 15, t >> 4, acc);
    __syncthreads();
  }
  int tx = t & 15, ty = t >> 4;
#pragma unroll
  for (int mi = 0; mi < 2; ++mi)
#pragma unroll
    for (int ni = 0; ni < 2; ++ni)
#pragma unroll
      for (int j = 0; j < 4; ++j) {
        int c = n0 + ni * 64 + tx * 4 + j;  // s'
        float bias = b2[c];
        int d0 = m0 + mi * 64 + ty * 4;
        size_t base = ((size_t)b * SEQ_ + c) * 512 + d0;
        float4 res = *(const float4*)(xtok + base);
        float4 o;
        o.x = res.x + gelu_exact(acc[mi][ni][0][j] + bias);
        o.y = res.y + gelu_exact(acc[mi][ni][1][j] + bias);
        o.z = res.z + gelu_exact(acc[mi][ni][2][j] + bias);
        o.w = res.w + gelu_exact(acc[mi][ni][3][j] + bias);
        *(float4*)(xsum + base) = o;
      }
}

// ------------------------------------------------------------------ G3 ----
// h = ln3(x_sum) @ W3 + b3 ; col 0 -> x_score, cols 1..512 -> x_proj
// grid (5, 512)
__global__ __launch_bounds__(256) void g3_kernel(const float* __restrict__ xsum,
    const float* __restrict__ mean, const float* __restrict__ rstd,
    const float* __restrict__ g3, const float* __restrict__ bl3,
    const float* __restrict__ W3, const float* __restrict__ b3,
    float* __restrict__ xscore, float* __restrict__ xproj) {
  __shared__ float As[16 * LSTR], Bs[16 * LSTR];
  int t = threadIdx.x;
  int m0 = blockIdx.y * 128, n0 = blockIdx.x * 128;
  float acc[2][2][4][4] = {};
  for (int k0 = 0; k0 < 512; k0 += 16) {
    load_a_ln(xsum, 512, mean, rstd, g3, bl3, m0, k0, As, t);
    {  // guarded scalar B loader (ldb = 513, unaligned rows)
      int kr = t >> 4;
      int nc = (t & 15) * 8;
      const float* src = W3 + (size_t)(k0 + kr) * 513 + n0 + nc;
#pragma unroll
      for (int i = 0; i < 8; ++i) {
        float v = (n0 + nc + i < 513) ? src[i] : 0.0f;
        Bs[kr * LSTR + nc + i] = v;
      }
    }
    __syncthreads();
    mm_tile(As, Bs, t & 15, t >> 4, acc);
    __syncthreads();
  }
  int tx = t & 15, ty = t >> 4;
#pragma unroll
  for (int mi = 0; mi < 2; ++mi)
#pragma unroll
    for (int ni = 0; ni < 2; ++ni)
#pragma unroll
      for (int i = 0; i < 4; ++i) {
        int r = m0 + mi * 64 + ty * 4 + i;
#pragma unroll
        for (int j = 0; j < 4; ++j) {
          int c = n0 + ni * 64 + tx * 4 + j;
          if (c < 513) {
            float v = acc[mi][ni][i][j] + b3[c];
            if (c == 0) xscore[r] = v;
            else xproj[(size_t)r * 512 + (c - 1)] = v;
          }
        }
      }
}

// ------------------------------------------------------------- diff_topk ----
// grid = 32 (one block per batch), block = 256; carry kept in registers.
__global__ __launch_bounds__(256) void topk_kernel(const float* __restrict__ xscore,
                                                   const float* __restrict__ tau,
                                                   float* __restrict__ Wm) {
  int b = blockIdx.x, t = threadIdx.x;
  __shared__ float red[4];
  float tv = fminf(fmaxf(tau[0], -2.0f), 5.0f);
  float temp = 1.0f / (1.0f + expf(-tv));
  float it = 1.0f / temp;
  float c[8];
  const float* xs = xscore + (size_t)b * SEQ_;
#pragma unroll
  for (int i = 0; i < 8; ++i) c[i] = xs[t * 8 + i];
  for (int k = 0; k < KSEL; ++k) {
    float e[8];
    float p = 0.f;
#pragma unroll
    for (int i = 0; i < 8; ++i) { e[i] = expf(c[i] * it); p += e[i]; }
#pragma unroll
    for (int off = 32; off > 0; off >>= 1) p += __shfl_down(p, off);
    if ((t & 63) == 0) red[t >> 6] = p;
    __syncthreads();
    float S = red[0] + red[1] + red[2] + red[3];
    float iS = 1.0f / S;
    float a[8];
#pragma unroll
    for (int i = 0; i < 8; ++i) a[i] = e[i] * iS;
    float* dst = Wm + ((size_t)b * KSEL + k) * SEQ_ + t * 8;
    *(float4*)(dst) = make_float4(a[0], a[1], a[2], a[3]);
    *(float4*)(dst + 4) = make_float4(a[4], a[5], a[6], a[7]);
#pragma unroll
    for (int i = 0; i < 8; ++i) c[i] += logf(fmaxf(1.0f - a[i], 1e-6f));
    __syncthreads();  // protect red[] before next iteration
  }
}

// ------------------------------------------------------------------ GZ ----
// Z[b] = Wmat[b] (128x2048) @ x_proj[b] (2048x512).  grid (4, 1, 32)
__global__ __launch_bounds__(256) void gz_kernel(const float* __restrict__ Wm,
    const float* __restrict__ xproj, float* __restrict__ Z) {
  __shared__ float As[16 * LSTR], Bs[16 * LSTR];
  int t = threadIdx.x;
  int b = blockIdx.z;
  int n0 = blockIdx.x * 128;
  const float* A = Wm + (size_t)b * KSEL * SEQ_;
  const float* Bm = xproj + (size_t)b * SEQ_ * 512;
  float acc[2][2][4][4] = {};
  for (int k0 = 0; k0 < 2048; k0 += 16) {
    load_a_plain(A, SEQ_, 0, k0, As, t);
    load_b_tile(Bm, 512, k0, n0, Bs, t);
    __syncthreads();
    mm_tile(As, Bs, t & 15, t >> 4, acc);
    __syncthreads();
  }
  int tx = t & 15, ty = t >> 4;
#pragma unroll
  for (int mi = 0; mi < 2; ++mi)
#pragma unroll
    for (int ni = 0; ni < 2; ++ni)
#pragma unroll
      for (int i = 0; i < 4; ++i) {
        int r = mi * 64 + ty * 4 + i;
        int cb = n0 + ni * 64 + tx * 4;
        float4 o = make_float4(acc[mi][ni][i][0], acc[mi][ni][i][1],
                               acc[mi][ni][i][2], acc[mi][ni][i][3]);
        *(float4*)(Z + ((size_t)b * KSEL + r) * 512 + cb) = o;
      }
}

// ------------------------------------------------------------------ GY ----
// r[b,s,d] = x_proj[b,s,d] + (Wmat[b]^T @ Z[b])[s,d].  grid (4, 16, 32)
__global__ __launch_bounds__(256) void gy_kernel(const float* __restrict__ Wm,
    const float* __restrict__ Z, const float* __restrict__ xproj,
    float* __restrict__ rbuf) {
  __shared__ float As[16 * LSTR], Bs[16 * LSTR];
  int t = threadIdx.x;
  int b = blockIdx.z;
  int m0 = blockIdx.y * 128, n0 = blockIdx.x * 128;
  float acc[2][2][4][4] = {};
  for (int k0 = 0; k0 < KSEL; k0 += 16) {
    {  // A = Wmat^T : As[k][s] = Wm[b][k][s], coalesced along s
      int kl = t >> 4;
      int sl = (t & 15) * 8;
      const float* src = Wm + ((size_t)b * KSEL + k0 + kl) * SEQ_ + m0 + sl;
      float4 v0 = *(const float4*)(src);
      float4 v1 = *(const float4*)(src + 4);
      *(float4*)(As + kl * LSTR + sl) = v0;
      *(float4*)(As + kl * LSTR + sl + 4) = v1;
    }
    load_b_tile(Z + (size_t)b * KSEL * 512, 512, k0, n0, Bs, t);
    __syncthreads();
    mm_tile(As, Bs, t & 15, t >> 4, acc);
    __syncthreads();
  }
  int tx = t & 15, ty = t >> 4;
#pragma unroll
  for (int mi = 0; mi < 2; ++mi)
#pragma unroll
    for (int ni = 0; ni < 2; ++ni) {
      int cb = n0 + ni * 64 + tx * 4;
#pragma unroll
      for (int i = 0; i < 4; ++i) {
        int r = m0 + mi * 64 + ty * 4 + i;
        size_t base = ((size_t)b * SEQ_ + r) * 512 + cb;
        float4 xp = *(const float4*)(xproj + base);
        float4 o;
        o.x = xp.x + acc[mi][ni][i][0];
        o.y = xp.y + acc[mi][ni][i][1];
        o.z = xp.z + acc[mi][ni][i][2];
        o.w = xp.w + acc[mi][ni][i][3];
        *(float4*)(rbuf + base) = o;
      }
    }
}

// ------------------------------------------------------------------ G4 ----
// out = ln4(r) @ W4 + b4.  grid (4, 512)
__global__ __launch_bounds__(256) void g4_kernel(const float* __restrict__ rbuf,
    const float* __restrict__ mean, const float* __restrict__ rstd,
    const float* __restrict__ g4, const float* __restrict__ bl4,
    const float* __restrict__ W4, const float* __restrict__ b4,
    float* __restrict__ out) {
  __shared__ float As[16 * LSTR], Bs[16 * LSTR];
  int t = threadIdx.x;
  int m0 = blockIdx.y * 128, n0 = blockIdx.x * 128;
  float acc[2][2][4][4] = {};
  for (int k0 = 0; k0 < 512; k0 += 16) {
    load_a_ln(rbuf, 512, mean, rstd, g4, bl4, m0, k0, As, t);
    load_b_tile(W4, 512, k0, n0, Bs, t);
    __syncthreads();
    mm_tile(As, Bs, t & 15, t >> 4, acc);
    __syncthreads();
  }
  int tx = t & 15, ty = t >> 4;
#pragma unroll
  for (int mi = 0; mi < 2; ++mi)
#pragma unroll
    for (int ni = 0; ni < 2; ++ni) {
      int cb = n0 + ni * 64 + tx * 4;
      float4 bias = *(const float4*)(b4 + cb);
#pragma unroll
      for (int i = 0; i < 4; ++i) {
        int r = m0 + mi * 64 + ty * 4 + i;
        float4 o;
        o.x = acc[mi][ni][i][0] + bias.x;
        o.y = acc[mi][ni][i][1] + bias.y;
        o.z = acc[mi][ni][i][2] + bias.z;
        o.w = acc[mi][ni][i][3] + bias.w;
        *(float4*)(out + (size_t)r * 512 + cb) = o;
      }
    }
}

// -------------------------------------------------------------- launcher ----
extern "C" void kernel_launch(void* const* d_in, const int* in_sizes, int n_in,
                              void* d_out, int out_size, void* d_ws, size_t ws_size,
                              hipStream_t stream) {
  const float* x    = (const float*)d_in[0];
  const float* tau  = (const float*)d_in[1];
  const float* g1   = (const float*)d_in[2];
  const float* bl1  = (const float*)d_in[3];
  const float* W1   = (const float*)d_in[4];
  const float* b1   = (const float*)d_in[5];
  const float* g2   = (const float*)d_in[6];
  const float* bl2  = (const float*)d_in[7];
  const float* W2   = (const float*)d_in[8];
  const float* b2   = (const float*)d_in[9];
  const float* g3   = (const float*)d_in[10];
  const float* bl3  = (const float*)d_in[11];
  const float* W3   = (const float*)d_in[12];
  const float* b3   = (const float*)d_in[13];
  const float* g4   = (const float*)d_in[14];
  const float* bl4  = (const float*)d_in[15];
  const float* W4   = (const float*)d_in[16];
  const float* b4   = (const float*)d_in[17];
  float* out = (float*)d_out;

  const size_t NTOK = (size_t)B_ * SEQ_;          // 65536 rows
  float* ws = (float*)d_ws;
  float* bufB   = ws;                              // x_sum, later r  (33.5M)
  float* Wm     = bufB + NTOK * 512;               // 8.39M
  float* Z      = Wm + (size_t)B_ * KSEL * SEQ_;   // 2.10M
  float* xscore = Z + (size_t)B_ * KSEL * 512;     // 65536
  float* mean   = xscore + NTOK;                   // 65536 (shared by all LNs)
  float* rstd   = mean + NTOK;                     // 65536
  float2* part  = (float2*)(rstd + NTOK);          // 131072 float2
  // bufA aliases d_out: holds x_tok (until G2), then x_proj (until G4 writes out)
  float* bufA = out;

  // 1) LN1 stats + G1 -> x_tok (bufA)
  rowstats512<<<NTOK / 4, 256, 0, stream>>>(x, mean, rstd);
  g1_kernel<<<dim3(4, 512), 256, 0, stream>>>(x, mean, rstd, g1, bl1, W1, b1, bufA);

  // 2) LN2 stats (over s) + G2 -> x_sum (bufB)
  colstats_part<<<B_ * 8, 512, 0, stream>>>(bufA, part);
  colstats_fin<<<64, 256, 0, stream>>>(part, mean, rstd);
  g2_kernel<<<dim3(16, 4, B_), 256, 0, stream>>>(bufA, mean, rstd, g2, bl2, W2, b2, bufB);

  // 3) LN3 stats + G3 -> x_score, x_proj (bufA; x_tok dead)
  rowstats512<<<NTOK / 4, 256, 0, stream>>>(bufB, mean, rstd);
  g3_kernel<<<dim3(5, 512), 256, 0, stream>>>(bufB, mean, rstd, g3, bl3, W3, b3, xscore, bufA);

  // 4) differentiable top-k -> Wmat
  topk_kernel<<<B_, 256, 0, stream>>>(xscore, tau, Wm);

  // 5) Z = Wmat @ x_proj
  gz_kernel<<<dim3(4, 1, B_), 256, 0, stream>>>(Wm, bufA, Z);

  // 6) r = x_proj + Wmat^T @ Z  (bufB; x_sum dead)
  gy_kernel<<<dim3(4, 16, B_), 256, 0, stream>>>(Wm, Z, bufA, bufB);

  // 7) LN4 stats + G4 -> out (x_proj dead)
  rowstats512<<<NTOK / 4, 256, 0, stream>>>(bufB, mean, rstd);
  g4_kernel<<<dim3(4, 512), 256, 0, stream>>>(bufB, mean, rstd, g4, bl4, W4, b4, out);
}

// Round 2
// 980.751 us; speedup vs baseline: 3.9666x; 3.9666x over previous
//
#include <hip/hip_runtime.h>
#include <math.h>

#define B_   32
#define SEQ_ 2048
#define DIM_ 512
#define KSEL 128

typedef _Float16 f16;
typedef _Float16 half8 __attribute__((ext_vector_type(8)));
typedef float floatx4 __attribute__((ext_vector_type(4)));

#define LSTRH 40   // LDS row stride in halves (80B: 2-way bank aliasing = free)

__device__ __forceinline__ float gelu_exact(float v) {
  return 0.5f * v * (1.0f + erff(v * 0.70710678118654752440f));
}

// ======================= stats kernels =======================
// mean/rstd of fp32 rows of length 512. grid = rows/4, block 256 (1 row/wave)
__global__ __launch_bounds__(256) void rowstats512(const float* __restrict__ X,
                                                   float* __restrict__ mean,
                                                   float* __restrict__ rstd) {
  int row = blockIdx.x * 4 + (threadIdx.x >> 6);
  int l = threadIdx.x & 63;
  const float4* p = (const float4*)(X + (size_t)row * 512);
  float4 v0 = p[l * 2], v1 = p[l * 2 + 1];
  float s = v0.x + v0.y + v0.z + v0.w + v1.x + v1.y + v1.z + v1.w;
  float q = v0.x*v0.x + v0.y*v0.y + v0.z*v0.z + v0.w*v0.w
          + v1.x*v1.x + v1.y*v1.y + v1.z*v1.z + v1.w*v1.w;
#pragma unroll
  for (int off = 32; off > 0; off >>= 1) {
    s += __shfl_down(s, off);
    q += __shfl_down(q, off);
  }
  if (l == 0) {
    float m = s * (1.0f / 512.0f);
    float var = q * (1.0f / 512.0f) - m * m;
    mean[row] = m;
    rstd[row] = rsqrtf(var + 1e-5f);
  }
}

// f16 variant
__global__ __launch_bounds__(256) void rowstats512_f16(const f16* __restrict__ X,
                                                       float* __restrict__ mean,
                                                       float* __restrict__ rstd) {
  int row = blockIdx.x * 4 + (threadIdx.x >> 6);
  int l = threadIdx.x & 63;
  half8 h = *(const half8*)(X + (size_t)row * 512 + l * 8);
  float s = 0.f, q = 0.f;
#pragma unroll
  for (int i = 0; i < 8; ++i) { float v = (float)h[i]; s += v; q += v * v; }
#pragma unroll
  for (int off = 32; off > 0; off >>= 1) {
    s += __shfl_down(s, off);
    q += __shfl_down(q, off);
  }
  if (l == 0) {
    float m = s * (1.0f / 512.0f);
    float var = q * (1.0f / 512.0f) - m * m;
    mean[row] = m;
    rstd[row] = rsqrtf(var + 1e-5f);
  }
}

// LN2 column stats over s of x_tok[b,s,d] (f16). Pass1 partials.
__global__ __launch_bounds__(512) void colstats_part(const f16* __restrict__ xtok,
                                                     float2* __restrict__ part) {
  int b = blockIdx.x >> 3, pr = blockIdx.x & 7;
  int d = threadIdx.x;
  const f16* src = xtok + ((size_t)b * SEQ_ + (size_t)pr * 256) * 512 + d;
  float s = 0.f, q = 0.f;
#pragma unroll 4
  for (int i = 0; i < 256; ++i) {
    float v = (float)src[(size_t)i * 512];
    s += v; q += v * v;
  }
  part[(size_t)blockIdx.x * 512 + d] = make_float2(s, q);
}

__global__ __launch_bounds__(256) void colstats_fin(const float2* __restrict__ part,
                                                    float* __restrict__ mean,
                                                    float* __restrict__ rstd) {
  int idx = blockIdx.x * 256 + threadIdx.x;
  int b = idx >> 9;
  float s = 0.f, q = 0.f;
#pragma unroll
  for (int p = 0; p < 8; ++p) {
    float2 v = part[((size_t)(b * 8 + p)) * 512 + (idx & 511)];
    s += v.x; q += v.y;
  }
  float m = s * (1.0f / 2048.0f);
  mean[idx] = m;
  rstd[idx] = rsqrtf(q * (1.0f / 2048.0f) - m * m + 1e-5f);
}

// ======================= transpose / convert =======================
// dst[c][r] = (f16)src[r][c], guarded; batched via blockIdx.z
template <typename T>
__global__ __launch_bounds__(256) void transpose_cvt(const T* __restrict__ src,
                                                     f16* __restrict__ dst,
                                                     int R, int C, long sb, long db) {
  __shared__ float tile[32][33];
  const T* s = src + (long)blockIdx.z * sb;
  f16* d = dst + (long)blockIdx.z * db;
  int c0 = blockIdx.x * 32, r0 = blockIdx.y * 32;
  int tx = threadIdx.x, ty = threadIdx.y;
#pragma unroll
  for (int i = 0; i < 4; ++i) {
    int r = r0 + ty + i * 8, c = c0 + tx;
    if (r < R && c < C) tile[ty + i * 8][tx] = (float)s[(long)r * C + c];
  }
  __syncthreads();
#pragma unroll
  for (int i = 0; i < 4; ++i) {
    int c = c0 + ty + i * 8, r = r0 + tx;
    if (c < C && r < R) d[(long)c * R + r] = (f16)tile[tx][ty + i * 8];
  }
}

// LN2-apply + transpose: A2[b][d][s] = (xtok[b][s][d]-m2[b,d])*r2[b,d]*g2[s]+bl2[s]
__global__ __launch_bounds__(256) void trans2_kernel(const f16* __restrict__ xtok,
    const float* __restrict__ mean2, const float* __restrict__ rstd2,
    const float* __restrict__ g2, const float* __restrict__ bl2,
    f16* __restrict__ A2) {
  __shared__ float tile[32][33];
  int b = blockIdx.z;
  const f16* src = xtok + (long)b * SEQ_ * 512;
  f16* dst = A2 + (long)b * 512 * SEQ_;
  int d0 = blockIdx.x * 32, s0 = blockIdx.y * 32;
  int tx = threadIdx.x, ty = threadIdx.y;
  float m = mean2[b * 512 + d0 + tx];
  float rs = rstd2[b * 512 + d0 + tx];
#pragma unroll
  for (int i = 0; i < 4; ++i) {
    int s = s0 + ty + i * 8;
    float v = (float)src[(long)s * 512 + d0 + tx];
    tile[ty + i * 8][tx] = (v - m) * rs * g2[s] + bl2[s];
  }
  __syncthreads();
#pragma unroll
  for (int i = 0; i < 4; ++i) {
    int d = d0 + ty + i * 8, s = s0 + tx;
    dst[(long)d * SEQ_ + s] = (f16)tile[tx][ty + i * 8];
  }
}

// ======================= GEMM core =======================
// 128x128 tile, BK=32, 256 threads = 4 waves (2x2), 4x4 16x16 frags per wave.

__device__ __forceinline__ void stage_f16(const f16* __restrict__ src, long ld,
                                          int row0, int k0, f16* S, int t) {
  int row = t >> 1, kc = (t & 1) * 16;
  const f16* p = src + (long)(row0 + row) * ld + k0 + kc;
  half8 v0 = *(const half8*)(p);
  half8 v1 = *(const half8*)(p + 8);
  *(half8*)(S + row * LSTRH + kc) = v0;
  *(half8*)(S + row * LSTRH + kc + 8) = v1;
}

__device__ __forceinline__ void stage_a_f32(const float* __restrict__ src, long ld,
                                            int row0, int k0, f16* S, int t) {
  int row = t >> 1, kc = (t & 1) * 16;
  const float* p = src + (long)(row0 + row) * ld + k0 + kc;
  float v[16];
#pragma unroll
  for (int i = 0; i < 4; ++i) {
    float4 q = ((const float4*)p)[i];
    v[i * 4 + 0] = q.x; v[i * 4 + 1] = q.y; v[i * 4 + 2] = q.z; v[i * 4 + 3] = q.w;
  }
  half8 o0, o1;
#pragma unroll
  for (int i = 0; i < 8; ++i) { o0[i] = (f16)v[i]; o1[i] = (f16)v[i + 8]; }
  *(half8*)(S + row * LSTRH + kc) = o0;
  *(half8*)(S + row * LSTRH + kc + 8) = o1;
}

__device__ __forceinline__ void stage_a_ln_f32(const float* __restrict__ src, long ld,
    const float* __restrict__ mean, const float* __restrict__ rstd,
    const float* __restrict__ g, const float* __restrict__ bl,
    int row0, int k0, f16* S, int t) {
  int row = t >> 1, kc = (t & 1) * 16;
  int r = row0 + row, c = k0 + kc;
  float m = mean[r], sd = rstd[r];
  const float* p = src + (long)r * ld + c;
  float v[16], gv[16], bv[16];
#pragma unroll
  for (int i = 0; i < 4; ++i) {
    float4 q = ((const float4*)p)[i];
    v[i*4+0]=q.x; v[i*4+1]=q.y; v[i*4+2]=q.z; v[i*4+3]=q.w;
    float4 gq = ((const float4*)(g + c))[i];
    gv[i*4+0]=gq.x; gv[i*4+1]=gq.y; gv[i*4+2]=gq.z; gv[i*4+3]=gq.w;
    float4 bq = ((const float4*)(bl + c))[i];
    bv[i*4+0]=bq.x; bv[i*4+1]=bq.y; bv[i*4+2]=bq.z; bv[i*4+3]=bq.w;
  }
  half8 o0, o1;
#pragma unroll
  for (int i = 0; i < 8; ++i) {
    o0[i] = (f16)((v[i] - m) * sd * gv[i] + bv[i]);
    o1[i] = (f16)((v[i + 8] - m) * sd * gv[i + 8] + bv[i + 8]);
  }
  *(half8*)(S + row * LSTRH + kc) = o0;
  *(half8*)(S + row * LSTRH + kc + 8) = o1;
}

__device__ __forceinline__ void stage_a_ln_f16(const f16* __restrict__ src, long ld,
    const float* __restrict__ mean, const float* __restrict__ rstd,
    const float* __restrict__ g, const float* __restrict__ bl,
    int row0, int k0, f16* S, int t) {
  int row = t >> 1, kc = (t & 1) * 16;
  int r = row0 + row, c = k0 + kc;
  float m = mean[r], sd = rstd[r];
  const f16* p = src + (long)r * ld + c;
  half8 h0 = *(const half8*)(p);
  half8 h1 = *(const half8*)(p + 8);
  float gv[16], bv[16];
#pragma unroll
  for (int i = 0; i < 4; ++i) {
    float4 gq = ((const float4*)(g + c))[i];
    gv[i*4+0]=gq.x; gv[i*4+1]=gq.y; gv[i*4+2]=gq.z; gv[i*4+3]=gq.w;
    float4 bq = ((const float4*)(bl + c))[i];
    bv[i*4+0]=bq.x; bv[i*4+1]=bq.y; bv[i*4+2]=bq.z; bv[i*4+3]=bq.w;
  }
  half8 o0, o1;
#pragma unroll
  for (int i = 0; i < 8; ++i) {
    o0[i] = (f16)(((float)h0[i] - m) * sd * gv[i] + bv[i]);
    o1[i] = (f16)(((float)h1[i] - m) * sd * gv[i + 8] + bv[i + 8]);
  }
  *(half8*)(S + row * LSTRH + kc) = o0;
  *(half8*)(S + row * LSTRH + kc + 8) = o1;
}

__device__ __forceinline__ void mfma_step(const f16* As, const f16* Bs, int lane,
                                          int wr, int wc, floatx4 acc[4][4]) {
  int kc = (lane >> 4) * 8;
  int rl = lane & 15;
  half8 a[4], b[4];
#pragma unroll
  for (int mi = 0; mi < 4; ++mi)
    a[mi] = *(const half8*)(As + (wr * 64 + mi * 16 + rl) * LSTRH + kc);
#pragma unroll
  for (int ni = 0; ni < 4; ++ni)
    b[ni] = *(const half8*)(Bs + (wc * 64 + ni * 16 + rl) * LSTRH + kc);
#pragma unroll
  for (int mi = 0; mi < 4; ++mi)
#pragma unroll
    for (int ni = 0; ni < 4; ++ni)
      acc[mi][ni] = __builtin_amdgcn_mfma_f32_16x16x32_f16(a[mi], b[ni], acc[mi][ni], 0, 0, 0);
}

#define GEMM_PROLOG \
  __shared__ f16 As[128 * LSTRH]; \
  __shared__ f16 Bs[128 * LSTRH]; \
  int t = threadIdx.x; \
  int lane = t & 63, w = t >> 6, wr = w >> 1, wc = w & 1; \
  floatx4 acc[4][4]; \
  _Pragma("unroll") for (int mi = 0; mi < 4; ++mi) \
  _Pragma("unroll") for (int ni = 0; ni < 4; ++ni) acc[mi][ni] = (floatx4){0.f,0.f,0.f,0.f};

// ---- G1: x_tok = gelu(ln1(x)@W1 + b1), f16 out.  grid (4, 512)
__global__ __launch_bounds__(256) void g1_kernel(const float* __restrict__ x,
    const float* __restrict__ mean, const float* __restrict__ rstd,
    const float* __restrict__ g1, const float* __restrict__ bl1,
    const f16* __restrict__ W1T, const float* __restrict__ b1,
    f16* __restrict__ xtok) {
  GEMM_PROLOG
  int m0 = blockIdx.y * 128, n0 = blockIdx.x * 128;
  for (int k0 = 0; k0 < 512; k0 += 32) {
    stage_a_ln_f32(x, 512, mean, rstd, g1, bl1, m0, k0, As, t);
    stage_f16(W1T, 512, n0, k0, Bs, t);
    __syncthreads();
    mfma_step(As, Bs, lane, wr, wc, acc);
    __syncthreads();
  }
#pragma unroll
  for (int mi = 0; mi < 4; ++mi)
#pragma unroll
    for (int ni = 0; ni < 4; ++ni) {
      int c = n0 + wc * 64 + ni * 16 + (lane & 15);
      float bias = b1[c];
      int r0 = m0 + wr * 64 + mi * 16 + (lane >> 4) * 4;
#pragma unroll
      for (int j = 0; j < 4; ++j)
        xtok[(long)(r0 + j) * 512 + c] = (f16)gelu_exact(acc[mi][ni][j] + bias);
    }
}

// ---- G2: x_sum[s',d] = xtok[s',d] + gelu( (W2T@A2^T) + b2[s'] ). grid (4,16,32)
__global__ __launch_bounds__(256) void g2_kernel(const f16* __restrict__ W2T,
    const f16* __restrict__ A2, const float* __restrict__ b2,
    const f16* __restrict__ xtok, f16* __restrict__ xsum) {
  GEMM_PROLOG
  int b = blockIdx.z;
  int m0 = blockIdx.y * 128, n0 = blockIdx.x * 128;
  const f16* A2b = A2 + (long)b * 512 * SEQ_;
  const f16* xtb = xtok + (long)b * SEQ_ * 512;
  f16* xsb = xsum + (long)b * SEQ_ * 512;
  for (int k0 = 0; k0 < SEQ_; k0 += 32) {
    stage_f16(W2T, SEQ_, m0, k0, As, t);
    stage_f16(A2b, SEQ_, n0, k0, Bs, t);
    __syncthreads();
    mfma_step(As, Bs, lane, wr, wc, acc);
    __syncthreads();
  }
#pragma unroll
  for (int mi = 0; mi < 4; ++mi)
#pragma unroll
    for (int ni = 0; ni < 4; ++ni) {
      int c = n0 + wc * 64 + ni * 16 + (lane & 15);
      int r0 = m0 + wr * 64 + mi * 16 + (lane >> 4) * 4;
#pragma unroll
      for (int j = 0; j < 4; ++j) {
        int r = r0 + j;
        long idx = (long)r * 512 + c;
        float v = gelu_exact(acc[mi][ni][j] + b2[r]);
        xsb[idx] = (f16)((float)xtb[idx] + v);
      }
    }
}

// ---- G3: xproj = ln3(xsum)@W3[:,1:] + b3[1:], f16 out. grid (4, 512)
__global__ __launch_bounds__(256) void g3_kernel(const f16* __restrict__ xsum,
    const float* __restrict__ mean, const float* __restrict__ rstd,
    const float* __restrict__ g3, const float* __restrict__ bl3,
    const f16* __restrict__ BT /* = W3T + 512 */, const float* __restrict__ b3,
    f16* __restrict__ xproj) {
  GEMM_PROLOG
  int m0 = blockIdx.y * 128, n0 = blockIdx.x * 128;
  for (int k0 = 0; k0 < 512; k0 += 32) {
    stage_a_ln_f16(xsum, 512, mean, rstd, g3, bl3, m0, k0, As, t);
    stage_f16(BT, 512, n0, k0, Bs, t);
    __syncthreads();
    mfma_step(As, Bs, lane, wr, wc, acc);
    __syncthreads();
  }
#pragma unroll
  for (int mi = 0; mi < 4; ++mi)
#pragma unroll
    for (int ni = 0; ni < 4; ++ni) {
      int c = n0 + wc * 64 + ni * 16 + (lane & 15);
      float bias = b3[c + 1];
      int r0 = m0 + wr * 64 + mi * 16 + (lane >> 4) * 4;
#pragma unroll
      for (int j = 0; j < 4; ++j)
        xproj[(long)(r0 + j) * 512 + c] = (f16)(acc[mi][ni][j] + bias);
    }
}

// ---- score: xscore[b,s] = ln3(xsum[s,:]) . W3[:,0] + b3[0]. grid rows/4
__global__ __launch_bounds__(256) void score_kernel(const f16* __restrict__ xsum,
    const float* __restrict__ mean, const float* __restrict__ rstd,
    const float* __restrict__ g3, const float* __restrict__ bl3,
    const f16* __restrict__ w3c /* W3T row 0 */, const float* __restrict__ b3,
    float* __restrict__ xscore) {
  int row = blockIdx.x * 4 + (threadIdx.x >> 6);
  int l = threadIdx.x & 63;
  float m = mean[row], sd = rstd[row];
  half8 h = *(const half8*)(xsum + (long)row * 512 + l * 8);
  half8 wv = *(const half8*)(w3c + l * 8);
  float acc = 0.f;
#pragma unroll
  for (int i = 0; i < 8; ++i) {
    int d = l * 8 + i;
    float v = ((float)h[i] - m) * sd * g3[d] + bl3[d];
    acc += v * (float)wv[i];
  }
#pragma unroll
  for (int off = 32; off > 0; off >>= 1) acc += __shfl_down(acc, off);
  if (l == 0) xscore[row] = acc + b3[0];
}

// ---- diff_topk (unchanged, fp32) ----
__global__ __launch_bounds__(256) void topk_kernel(const float* __restrict__ xscore,
                                                   const float* __restrict__ tau,
                                                   float* __restrict__ Wm) {
  int b = blockIdx.x, t = threadIdx.x;
  __shared__ float red[4];
  float tv = fminf(fmaxf(tau[0], -2.0f), 5.0f);
  float temp = 1.0f / (1.0f + expf(-tv));
  float it = 1.0f / temp;
  float c[8];
  const float* xs = xscore + (size_t)b * SEQ_;
#pragma unroll
  for (int i = 0; i < 8; ++i) c[i] = xs[t * 8 + i];
  for (int k = 0; k < KSEL; ++k) {
    float e[8];
    float p = 0.f;
#pragma unroll
    for (int i = 0; i < 8; ++i) { e[i] = expf(c[i] * it); p += e[i]; }
#pragma unroll
    for (int off = 32; off > 0; off >>= 1) p += __shfl_down(p, off);
    if ((t & 63) == 0) red[t >> 6] = p;
    __syncthreads();
    float S = red[0] + red[1] + red[2] + red[3];
    float iS = 1.0f / S;
    float a[8];
#pragma unroll
    for (int i = 0; i < 8; ++i) a[i] = e[i] * iS;
    float* dst = Wm + ((size_t)b * KSEL + k) * SEQ_ + t * 8;
    *(float4*)(dst) = make_float4(a[0], a[1], a[2], a[3]);
    *(float4*)(dst + 4) = make_float4(a[4], a[5], a[6], a[7]);
#pragma unroll
    for (int i = 0; i < 8; ++i) c[i] += logf(fmaxf(1.0f - a[i], 1e-6f));
    __syncthreads();
  }
}

// ---- GZ: Z[b] = Wm[b] @ xproj[b]  (fp32 out). grid (4, 1, 32)
__global__ __launch_bounds__(256) void gz_kernel(const float* __restrict__ Wm,
    const f16* __restrict__ xprojT, float* __restrict__ Z) {
  GEMM_PROLOG
  int b = blockIdx.z;
  int n0 = blockIdx.x * 128;
  const float* A = Wm + (long)b * KSEL * SEQ_;
  const f16* BT = xprojT + (long)b * 512 * SEQ_;
  float* Zb = Z + (long)b * KSEL * 512;
  for (int k0 = 0; k0 < SEQ_; k0 += 32) {
    stage_a_f32(A, SEQ_, 0, k0, As, t);
    stage_f16(BT, SEQ_, n0, k0, Bs, t);
    __syncthreads();
    mfma_step(As, Bs, lane, wr, wc, acc);
    __syncthreads();
  }
#pragma unroll
  for (int mi = 0; mi < 4; ++mi)
#pragma unroll
    for (int ni = 0; ni < 4; ++ni) {
      int c = n0 + wc * 64 + ni * 16 + (lane & 15);
      int r0 = wr * 64 + mi * 16 + (lane >> 4) * 4;
#pragma unroll
      for (int j = 0; j < 4; ++j)
        Zb[(long)(r0 + j) * 512 + c] = acc[mi][ni][j];
    }
}

// ---- GY: rbuf = xproj + Wm^T @ Z. grid (4, 16, 32)
__global__ __launch_bounds__(256) void gy_kernel(const f16* __restrict__ WmT,
    const f16* __restrict__ ZT, const f16* __restrict__ xproj,
    f16* __restrict__ rbuf) {
  GEMM_PROLOG
  int b = blockIdx.z;
  int m0 = blockIdx.y * 128, n0 = blockIdx.x * 128;
  const f16* A = WmT + (long)b * SEQ_ * KSEL;
  const f16* BT = ZT + (long)b * 512 * KSEL;
  const f16* xpb = xproj + (long)b * SEQ_ * 512;
  f16* rb = rbuf + (long)b * SEQ_ * 512;
  for (int k0 = 0; k0 < KSEL; k0 += 32) {
    stage_f16(A, KSEL, m0, k0, As, t);
    stage_f16(BT, KSEL, n0, k0, Bs, t);
    __syncthreads();
    mfma_step(As, Bs, lane, wr, wc, acc);
    __syncthreads();
  }
#pragma unroll
  for (int mi = 0; mi < 4; ++mi)
#pragma unroll
    for (int ni = 0; ni < 4; ++ni) {
      int c = n0 + wc * 64 + ni * 16 + (lane & 15);
      int r0 = m0 + wr * 64 + mi * 16 + (lane >> 4) * 4;
#pragma unroll
      for (int j = 0; j < 4; ++j) {
        long idx = (long)(r0 + j) * 512 + c;
        rb[idx] = (f16)((float)xpb[idx] + acc[mi][ni][j]);
      }
    }
}

// ---- G4: out = ln4(rbuf)@W4 + b4 (fp32 out). grid (4, 512)
__global__ __launch_bounds__(256) void g4_kernel(const f16* __restrict__ rbuf,
    const float* __restrict__ mean, const float* __restrict__ rstd,
    const float* __restrict__ g4, const float* __restrict__ bl4,
    const f16* __restrict__ W4T, const float* __restrict__ b4,
    float* __restrict__ out) {
  GEMM_PROLOG
  int m0 = blockIdx.y * 128, n0 = blockIdx.x * 128;
  for (int k0 = 0; k0 < 512; k0 += 32) {
    stage_a_ln_f16(rbuf, 512, mean, rstd, g4, bl4, m0, k0, As, t);
    stage_f16(W4T, 512, n0, k0, Bs, t);
    __syncthreads();
    mfma_step(As, Bs, lane, wr, wc, acc);
    __syncthreads();
  }
#pragma unroll
  for (int mi = 0; mi < 4; ++mi)
#pragma unroll
    for (int ni = 0; ni < 4; ++ni) {
      int c = n0 + wc * 64 + ni * 16 + (lane & 15);
      float bias = b4[c];
      int r0 = m0 + wr * 64 + mi * 16 + (lane >> 4) * 4;
#pragma unroll
      for (int j = 0; j < 4; ++j)
        out[(long)(r0 + j) * 512 + c] = acc[mi][ni][j] + bias;
    }
}

// ======================= launcher =======================
extern "C" void kernel_launch(void* const* d_in, const int* in_sizes, int n_in,
                              void* d_out, int out_size, void* d_ws, size_t ws_size,
                              hipStream_t stream) {
  const float* x    = (const float*)d_in[0];
  const float* tau  = (const float*)d_in[1];
  const float* g1   = (const float*)d_in[2];
  const float* bl1  = (const float*)d_in[3];
  const float* W1   = (const float*)d_in[4];
  const float* b1   = (const float*)d_in[5];
  const float* g2   = (const float*)d_in[6];
  const float* bl2  = (const float*)d_in[7];
  const float* W2   = (const float*)d_in[8];
  const float* b2   = (const float*)d_in[9];
  const float* g3   = (const float*)d_in[10];
  const float* bl3  = (const float*)d_in[11];
  const float* W3   = (const float*)d_in[12];
  const float* b3   = (const float*)d_in[13];
  const float* g4   = (const float*)d_in[14];
  const float* bl4  = (const float*)d_in[15];
  const float* W4   = (const float*)d_in[16];
  const float* b4   = (const float*)d_in[17];
  float* out = (float*)d_out;

  const long NTOK = (long)B_ * SEQ_;  // 65536

  // ---- workspace layout (bytes) ----
  char* ws = (char*)d_ws;
  f16* regA   = (f16*)(ws);                         // 64MB: A2, later xproj
  f16* regB   = (f16*)(ws + (64l << 20));           // 64MB: xsum, later rbuf
  float* Z    = (float*)(ws + (128l << 20));        // 8MB
  f16* ZT     = (f16*)(ws + (136l << 20));          // 4MB
  f16* WmT    = (f16*)(ws + (140l << 20));          // 16MB
  f16* W1T    = (f16*)(ws + (156l << 20));          // 0.5MB
  f16* W2T    = (f16*)(ws + (157l << 20));          // 8MB
  f16* W3T    = (f16*)(ws + (165l << 20));          // 513*512*2 = 0.5MB
  f16* W4T    = (f16*)(ws + (166l << 20));          // 0.5MB
  float* xscore = (float*)(ws + (167l << 20));      // 0.25MB
  float* meanA  = (float*)(ws + (168l << 20));      // 0.25MB
  float* rstdA  = meanA + NTOK;                     // 0.25MB
  float* mean2  = rstdA + NTOK;                     // 64KB
  float* rstd2  = mean2 + B_ * 512;                 // 64KB
  float2* part  = (float2*)(rstd2 + B_ * 512);      // 1MB

  // d_out doubles as scratch, fully overwritten by G4 at the end
  f16* xtok   = (f16*)d_out;                        // [0, 64MB)
  float* Wm   = (float*)((char*)d_out + (64l << 20));  // [64, 96MB)
  f16* xprojT = (f16*)d_out;                        // reuse after xtok dead

  f16* A2    = regA;
  f16* xsum  = regB;
  f16* xproj = regA;   // A2 dead after G2
  f16* rbuf  = regB;   // xsum dead after G3

  dim3 tb(32, 8);

  // weight transposes (f16, [n][k])
  transpose_cvt<float><<<dim3(16, 16, 1), tb, 0, stream>>>(W1, W1T, 512, 512, 0, 0);
  transpose_cvt<float><<<dim3(64, 64, 1), tb, 0, stream>>>(W2, W2T, 2048, 2048, 0, 0);
  transpose_cvt<float><<<dim3(17, 16, 1), tb, 0, stream>>>(W3, W3T, 512, 513, 0, 0);
  transpose_cvt<float><<<dim3(16, 16, 1), tb, 0, stream>>>(W4, W4T, 512, 512, 0, 0);

  // 1) LN1 stats + G1 -> xtok (f16, in d_out)
  rowstats512<<<NTOK / 4, 256, 0, stream>>>(x, meanA, rstdA);
  g1_kernel<<<dim3(4, 512), 256, 0, stream>>>(x, meanA, rstdA, g1, bl1, W1T, b1, xtok);

  // 2) LN2 stats + transposed normalize -> A2, then G2 -> xsum
  colstats_part<<<B_ * 8, 512, 0, stream>>>(xtok, part);
  colstats_fin<<<64, 256, 0, stream>>>(part, mean2, rstd2);
  trans2_kernel<<<dim3(16, 64, B_), tb, 0, stream>>>(xtok, mean2, rstd2, g2, bl2, A2);
  g2_kernel<<<dim3(4, 16, B_), 256, 0, stream>>>(W2T, A2, b2, xtok, xsum);

  // 3) LN3 stats, score column, G3 -> xproj (overwrites A2)
  rowstats512_f16<<<NTOK / 4, 256, 0, stream>>>(xsum, meanA, rstdA);
  score_kernel<<<NTOK / 4, 256, 0, stream>>>(xsum, meanA, rstdA, g3, bl3, W3T, b3, xscore);
  g3_kernel<<<dim3(4, 512), 256, 0, stream>>>(xsum, meanA, rstdA, g3, bl3, W3T + 512, b3, xproj);

  // 4) top-k -> Wm (fp32, in d_out high half)
  topk_kernel<<<B_, 256, 0, stream>>>(xscore, tau, Wm);

  // 5) transposes for GZ/GY operands
  transpose_cvt<f16><<<dim3(16, 64, B_), tb, 0, stream>>>(xproj, xprojT, 2048, 512,
      (long)SEQ_ * 512, (long)512 * SEQ_);
  transpose_cvt<float><<<dim3(64, 4, B_), tb, 0, stream>>>(Wm, WmT, 128, 2048,
      (long)KSEL * SEQ_, (long)SEQ_ * KSEL);

  // 6) Z = Wm @ xproj
  gz_kernel<<<dim3(4, 1, B_), 256, 0, stream>>>(Wm, xprojT, Z);
  transpose_cvt<float><<<dim3(16, 4, B_), tb, 0, stream>>>(Z, ZT, 128, 512,
      (long)KSEL * 512, (long)512 * KSEL);

  // 7) rbuf = xproj + Wm^T @ Z (overwrites xsum)
  gy_kernel<<<dim3(4, 16, B_), 256, 0, stream>>>(WmT, ZT, xproj, rbuf);

  // 8) LN4 stats + G4 -> out
  rowstats512_f16<<<NTOK / 4, 256, 0, stream>>>(rbuf, meanA, rstdA);
  g4_kernel<<<dim3(4, 512), 256, 0, stream>>>(rbuf, meanA, rstdA, g4, bl4, W4T, b4, out);
}

// Round 4
// 878.291 us; speedup vs baseline: 4.4294x; 1.1167x over previous
//
#include <hip/hip_runtime.h>
#include <math.h>

#define B_   32
#define SEQ_ 2048
#define DIM_ 512
#define KSEL 128

typedef _Float16 f16;
typedef _Float16 half8 __attribute__((ext_vector_type(8)));
typedef float floatx4 __attribute__((ext_vector_type(4)));

#define LSTR2 32   // linear LDS row stride in halves (64B rows) for gll staging

__device__ __forceinline__ float gelu_exact(float v) {
  return 0.5f * v * (1.0f + erff(v * 0.70710678118654752440f));
}

// ======================= stats kernels =======================
__global__ __launch_bounds__(256) void rowstats512(const float* __restrict__ X,
                                                   float* __restrict__ mean,
                                                   float* __restrict__ rstd) {
  int row = blockIdx.x * 4 + (threadIdx.x >> 6);
  int l = threadIdx.x & 63;
  const float4* p = (const float4*)(X + (size_t)row * 512);
  float4 v0 = p[l * 2], v1 = p[l * 2 + 1];
  float s = v0.x + v0.y + v0.z + v0.w + v1.x + v1.y + v1.z + v1.w;
  float q = v0.x*v0.x + v0.y*v0.y + v0.z*v0.z + v0.w*v0.w
          + v1.x*v1.x + v1.y*v1.y + v1.z*v1.z + v1.w*v1.w;
#pragma unroll
  for (int off = 32; off > 0; off >>= 1) {
    s += __shfl_down(s, off);
    q += __shfl_down(q, off);
  }
  if (l == 0) {
    float m = s * (1.0f / 512.0f);
    float var = q * (1.0f / 512.0f) - m * m;
    mean[row] = m;
    rstd[row] = rsqrtf(var + 1e-5f);
  }
}

__global__ __launch_bounds__(256) void rowstats512_f16(const f16* __restrict__ X,
                                                       float* __restrict__ mean,
                                                       float* __restrict__ rstd) {
  int row = blockIdx.x * 4 + (threadIdx.x >> 6);
  int l = threadIdx.x & 63;
  half8 h = *(const half8*)(X + (size_t)row * 512 + l * 8);
  float s = 0.f, q = 0.f;
#pragma unroll
  for (int i = 0; i < 8; ++i) { float v = (float)h[i]; s += v; q += v * v; }
#pragma unroll
  for (int off = 32; off > 0; off >>= 1) {
    s += __shfl_down(s, off);
    q += __shfl_down(q, off);
  }
  if (l == 0) {
    float m = s * (1.0f / 512.0f);
    float var = q * (1.0f / 512.0f) - m * m;
    mean[row] = m;
    rstd[row] = rsqrtf(var + 1e-5f);
  }
}

__global__ __launch_bounds__(512) void colstats_part(const f16* __restrict__ xtok,
                                                     float2* __restrict__ part) {
  int b = blockIdx.x >> 3, pr = blockIdx.x & 7;
  int d = threadIdx.x;
  const f16* src = xtok + ((size_t)b * SEQ_ + (size_t)pr * 256) * 512 + d;
  float s = 0.f, q = 0.f;
#pragma unroll 4
  for (int i = 0; i < 256; ++i) {
    float v = (float)src[(size_t)i * 512];
    s += v; q += v * v;
  }
  part[(size_t)blockIdx.x * 512 + d] = make_float2(s, q);
}

__global__ __launch_bounds__(256) void colstats_fin(const float2* __restrict__ part,
                                                    float* __restrict__ mean,
                                                    float* __restrict__ rstd) {
  int idx = blockIdx.x * 256 + threadIdx.x;
  int b = idx >> 9;
  float s = 0.f, q = 0.f;
#pragma unroll
  for (int p = 0; p < 8; ++p) {
    float2 v = part[((size_t)(b * 8 + p)) * 512 + (idx & 511)];
    s += v.x; q += v.y;
  }
  float m = s * (1.0f / 2048.0f);
  mean[idx] = m;
  rstd[idx] = rsqrtf(q * (1.0f / 2048.0f) - m * m + 1e-5f);
}

// ======================= transpose / convert =======================
template <typename T>
__global__ __launch_bounds__(256) void transpose_cvt(const T* __restrict__ src,
                                                     f16* __restrict__ dst,
                                                     int R, int C, long sb, long db) {
  __shared__ float tile[32][33];
  const T* s = src + (long)blockIdx.z * sb;
  f16* d = dst + (long)blockIdx.z * db;
  int c0 = blockIdx.x * 32, r0 = blockIdx.y * 32;
  int tx = threadIdx.x, ty = threadIdx.y;
#pragma unroll
  for (int i = 0; i < 4; ++i) {
    int r = r0 + ty + i * 8, c = c0 + tx;
    if (r < R && c < C) tile[ty + i * 8][tx] = (float)s[(long)r * C + c];
  }
  __syncthreads();
#pragma unroll
  for (int i = 0; i < 4; ++i) {
    int c = c0 + ty + i * 8, r = r0 + tx;
    if (c < C && r < R) d[(long)c * R + r] = (f16)tile[tx][ty + i * 8];
  }
}

// LN2-apply + transpose: A2[b][d][s] = (xtok[b][s][d]-m2[b,d])*r2[b,d]*g2[s]+bl2[s]
__global__ __launch_bounds__(256) void trans2_kernel(const f16* __restrict__ xtok,
    const float* __restrict__ mean2, const float* __restrict__ rstd2,
    const float* __restrict__ g2, const float* __restrict__ bl2,
    f16* __restrict__ A2) {
  __shared__ float tile[32][33];
  int b = blockIdx.z;
  const f16* src = xtok + (long)b * SEQ_ * 512;
  f16* dst = A2 + (long)b * 512 * SEQ_;
  int d0 = blockIdx.x * 32, s0 = blockIdx.y * 32;
  int tx = threadIdx.x, ty = threadIdx.y;
  float m = mean2[b * 512 + d0 + tx];
  float rs = rstd2[b * 512 + d0 + tx];
#pragma unroll
  for (int i = 0; i < 4; ++i) {
    int s = s0 + ty + i * 8;
    float v = (float)src[(long)s * 512 + d0 + tx];
    tile[ty + i * 8][tx] = (v - m) * rs * g2[s] + bl2[s];
  }
  __syncthreads();
#pragma unroll
  for (int i = 0; i < 4; ++i) {
    int d = d0 + ty + i * 8, s = s0 + tx;
    dst[(long)d * SEQ_ + s] = (f16)tile[tx][ty + i * 8];
  }
}

// ======================= GEMM core (m97 structure) =======================
// 128x128 tile, BK=32 halves, 256 threads = 4 waves (2x2), 4x4 16x16 frags/wave.
// LDS: linear [128][32] halves per tile (64B rows), staged via global_load_lds.

// async stage of one 128x32-half tile; LDS dst is wave-uniform, global src per-lane
__device__ __forceinline__ void stage_gll(const f16* __restrict__ src, long ld,
                                          int row0, int k0, f16* S, int t) {
  int w = t >> 6, lane = t & 63;
  int r = lane >> 2, c8 = (lane & 3) * 8;
#pragma unroll
  for (int i = 0; i < 2; ++i) {
    int chunk = w * 2 + i;
    const f16* g = src + (long)(row0 + chunk * 16 + r) * ld + k0 + c8;
    f16* l = S + chunk * 16 * LSTR2;   // wave-uniform base; HW adds lane*16
    __builtin_amdgcn_global_load_lds(
        (const __attribute__((address_space(1))) void*)g,
        (__attribute__((address_space(3))) void*)l, 16, 0, 0);
  }
}

// reg-staged A with layernorm fused, fp32 source
__device__ __forceinline__ void stage_a_ln_f32(const float* __restrict__ src, long ld,
    const float* __restrict__ mean, const float* __restrict__ rstd,
    const float* __restrict__ g, const float* __restrict__ bl,
    int row0, int k0, f16* S, int t) {
  int row = t >> 1, kc = (t & 1) * 16;
  int r = row0 + row, c = k0 + kc;
  float m = mean[r], sd = rstd[r];
  const float* p = src + (long)r * ld + c;
  float v[16], gv[16], bv[16];
#pragma unroll
  for (int i = 0; i < 4; ++i) {
    float4 q = ((const float4*)p)[i];
    v[i*4+0]=q.x; v[i*4+1]=q.y; v[i*4+2]=q.z; v[i*4+3]=q.w;
    float4 gq = ((const float4*)(g + c))[i];
    gv[i*4+0]=gq.x; gv[i*4+1]=gq.y; gv[i*4+2]=gq.z; gv[i*4+3]=gq.w;
    float4 bq = ((const float4*)(bl + c))[i];
    bv[i*4+0]=bq.x; bv[i*4+1]=bq.y; bv[i*4+2]=bq.z; bv[i*4+3]=bq.w;
  }
  half8 o0, o1;
#pragma unroll
  for (int i = 0; i < 8; ++i) {
    o0[i] = (f16)((v[i] - m) * sd * gv[i] + bv[i]);
    o1[i] = (f16)((v[i + 8] - m) * sd * gv[i + 8] + bv[i + 8]);
  }
  *(half8*)(S + row * LSTR2 + kc) = o0;
  *(half8*)(S + row * LSTR2 + kc + 8) = o1;
}

// reg-staged A with layernorm fused, f16 source
__device__ __forceinline__ void stage_a_ln_f16(const f16* __restrict__ src, long ld,
    const float* __restrict__ mean, const float* __restrict__ rstd,
    const float* __restrict__ g, const float* __restrict__ bl,
    int row0, int k0, f16* S, int t) {
  int row = t >> 1, kc = (t & 1) * 16;
  int r = row0 + row, c = k0 + kc;
  float m = mean[r], sd = rstd[r];
  const f16* p = src + (long)r * ld + c;
  half8 h0 = *(const half8*)(p);
  half8 h1 = *(const half8*)(p + 8);
  float gv[16], bv[16];
#pragma unroll
  for (int i = 0; i < 4; ++i) {
    float4 gq = ((const float4*)(g + c))[i];
    gv[i*4+0]=gq.x; gv[i*4+1]=gq.y; gv[i*4+2]=gq.z; gv[i*4+3]=gq.w;
    float4 bq = ((const float4*)(bl + c))[i];
    bv[i*4+0]=bq.x; bv[i*4+1]=bq.y; bv[i*4+2]=bq.z; bv[i*4+3]=bq.w;
  }
  half8 o0, o1;
#pragma unroll
  for (int i = 0; i < 8; ++i) {
    o0[i] = (f16)(((float)h0[i] - m) * sd * gv[i] + bv[i]);
    o1[i] = (f16)(((float)h1[i] - m) * sd * gv[i + 8] + bv[i + 8]);
  }
  *(half8*)(S + row * LSTR2 + kc) = o0;
  *(half8*)(S + row * LSTR2 + kc + 8) = o1;
}

__device__ __forceinline__ void mfma_step(const f16* As, const f16* Bs, int lane,
                                          int wr, int wc, floatx4 acc[4][4]) {
  int kc = (lane >> 4) * 8;
  int rl = lane & 15;
  half8 a[4], b[4];
#pragma unroll
  for (int mi = 0; mi < 4; ++mi)
    a[mi] = *(const half8*)(As + (wr * 64 + mi * 16 + rl) * LSTR2 + kc);
#pragma unroll
  for (int ni = 0; ni < 4; ++ni)
    b[ni] = *(const half8*)(Bs + (wc * 64 + ni * 16 + rl) * LSTR2 + kc);
#pragma unroll
  for (int mi = 0; mi < 4; ++mi)
#pragma unroll
    for (int ni = 0; ni < 4; ++ni)
      acc[mi][ni] = __builtin_amdgcn_mfma_f32_16x16x32_f16(a[mi], b[ni], acc[mi][ni], 0, 0, 0);
}

#define GEMM_PROLOG \
  __shared__ __attribute__((aligned(16))) f16 As[128 * LSTR2]; \
  __shared__ __attribute__((aligned(16))) f16 Bs[128 * LSTR2]; \
  int t = threadIdx.x; \
  int lane = t & 63, w = t >> 6, wr = w >> 1, wc = w & 1; \
  floatx4 acc[4][4]; \
  _Pragma("unroll") for (int mi = 0; mi < 4; ++mi) \
  _Pragma("unroll") for (int ni = 0; ni < 4; ++ni) acc[mi][ni] = (floatx4){0.f,0.f,0.f,0.f};

// ---- G1: x_tok = gelu(ln1(x)@W1 + b1), f16 out.  grid (4, 512)
__global__ __launch_bounds__(256) void g1_kernel(const float* __restrict__ x,
    const float* __restrict__ mean, const float* __restrict__ rstd,
    const float* __restrict__ g1, const float* __restrict__ bl1,
    const f16* __restrict__ W1T, const float* __restrict__ b1,
    f16* __restrict__ xtok) {
  GEMM_PROLOG
  int m0 = blockIdx.y * 128, n0 = blockIdx.x * 128;
  for (int k0 = 0; k0 < 512; k0 += 32) {
    stage_a_ln_f32(x, 512, mean, rstd, g1, bl1, m0, k0, As, t);
    stage_gll(W1T, 512, n0, k0, Bs, t);
    __syncthreads();
    mfma_step(As, Bs, lane, wr, wc, acc);
    __syncthreads();
  }
#pragma unroll
  for (int mi = 0; mi < 4; ++mi)
#pragma unroll
    for (int ni = 0; ni < 4; ++ni) {
      int c = n0 + wc * 64 + ni * 16 + (lane & 15);
      float bias = b1[c];
      int r0 = m0 + wr * 64 + mi * 16 + (lane >> 4) * 4;
#pragma unroll
      for (int j = 0; j < 4; ++j)
        xtok[(long)(r0 + j) * 512 + c] = (f16)gelu_exact(acc[mi][ni][j] + bias);
    }
}

// ---- G2: x_sum[s',d] = xtok[s',d] + gelu( (W2T@A2^T) + b2[s'] ). grid (4,16,32)
__global__ __launch_bounds__(256) void g2_kernel(const f16* __restrict__ W2T,
    const f16* __restrict__ A2, const float* __restrict__ b2,
    const f16* __restrict__ xtok, f16* __restrict__ xsum) {
  GEMM_PROLOG
  int b = blockIdx.z;
  int m0 = blockIdx.y * 128, n0 = blockIdx.x * 128;
  const f16* A2b = A2 + (long)b * 512 * SEQ_;
  const f16* xtb = xtok + (long)b * SEQ_ * 512;
  f16* xsb = xsum + (long)b * SEQ_ * 512;
  for (int k0 = 0; k0 < SEQ_; k0 += 32) {
    stage_gll(W2T, SEQ_, m0, k0, As, t);
    stage_gll(A2b, SEQ_, n0, k0, Bs, t);
    __syncthreads();
    mfma_step(As, Bs, lane, wr, wc, acc);
    __syncthreads();
  }
#pragma unroll
  for (int mi = 0; mi < 4; ++mi)
#pragma unroll
    for (int ni = 0; ni < 4; ++ni) {
      int c = n0 + wc * 64 + ni * 16 + (lane & 15);
      int r0 = m0 + wr * 64 + mi * 16 + (lane >> 4) * 4;
#pragma unroll
      for (int j = 0; j < 4; ++j) {
        int r = r0 + j;
        long idx = (long)r * 512 + c;
        float v = gelu_exact(acc[mi][ni][j] + b2[r]);
        xsb[idx] = (f16)((float)xtb[idx] + v);
      }
    }
}

// ---- G3: xproj = ln3(xsum)@W3[:,1:] + b3[1:], f16 out. grid (4, 512)
__global__ __launch_bounds__(256) void g3_kernel(const f16* __restrict__ xsum,
    const float* __restrict__ mean, const float* __restrict__ rstd,
    const float* __restrict__ g3, const float* __restrict__ bl3,
    const f16* __restrict__ BT /* = W3T + 512 */, const float* __restrict__ b3,
    f16* __restrict__ xproj) {
  GEMM_PROLOG
  int m0 = blockIdx.y * 128, n0 = blockIdx.x * 128;
  for (int k0 = 0; k0 < 512; k0 += 32) {
    stage_a_ln_f16(xsum, 512, mean, rstd, g3, bl3, m0, k0, As, t);
    stage_gll(BT, 512, n0, k0, Bs, t);
    __syncthreads();
    mfma_step(As, Bs, lane, wr, wc, acc);
    __syncthreads();
  }
#pragma unroll
  for (int mi = 0; mi < 4; ++mi)
#pragma unroll
    for (int ni = 0; ni < 4; ++ni) {
      int c = n0 + wc * 64 + ni * 16 + (lane & 15);
      float bias = b3[c + 1];
      int r0 = m0 + wr * 64 + mi * 16 + (lane >> 4) * 4;
#pragma unroll
      for (int j = 0; j < 4; ++j)
        xproj[(long)(r0 + j) * 512 + c] = (f16)(acc[mi][ni][j] + bias);
    }
}

// ---- score: xscore[b,s] = ln3(xsum[s,:]) . W3[:,0] + b3[0]. grid rows/4
__global__ __launch_bounds__(256) void score_kernel(const f16* __restrict__ xsum,
    const float* __restrict__ mean, const float* __restrict__ rstd,
    const float* __restrict__ g3, const float* __restrict__ bl3,
    const f16* __restrict__ w3c /* W3T row 0 */, const float* __restrict__ b3,
    float* __restrict__ xscore) {
  int row = blockIdx.x * 4 + (threadIdx.x >> 6);
  int l = threadIdx.x & 63;
  float m = mean[row], sd = rstd[row];
  half8 h = *(const half8*)(xsum + (long)row * 512 + l * 8);
  half8 wv = *(const half8*)(w3c + l * 8);
  float acc = 0.f;
#pragma unroll
  for (int i = 0; i < 8; ++i) {
    int d = l * 8 + i;
    float v = ((float)h[i] - m) * sd * g3[d] + bl3[d];
    acc += v * (float)wv[i];
  }
#pragma unroll
  for (int off = 32; off > 0; off >>= 1) acc += __shfl_down(acc, off);
  if (l == 0) xscore[row] = acc + b3[0];
}

// ---- diff_topk: fp32 internal, f16 Wm output ----
__global__ __launch_bounds__(256) void topk_kernel(const float* __restrict__ xscore,
                                                   const float* __restrict__ tau,
                                                   f16* __restrict__ Wm) {
  int b = blockIdx.x, t = threadIdx.x;
  __shared__ float red[4];
  float tv = fminf(fmaxf(tau[0], -2.0f), 5.0f);
  float temp = 1.0f / (1.0f + expf(-tv));
  float it = 1.0f / temp;
  float c[8];
  const float* xs = xscore + (size_t)b * SEQ_;
#pragma unroll
  for (int i = 0; i < 8; ++i) c[i] = xs[t * 8 + i];
  for (int k = 0; k < KSEL; ++k) {
    float e[8];
    float p = 0.f;
#pragma unroll
    for (int i = 0; i < 8; ++i) { e[i] = expf(c[i] * it); p += e[i]; }
#pragma unroll
    for (int off = 32; off > 0; off >>= 1) p += __shfl_down(p, off);
    if ((t & 63) == 0) red[t >> 6] = p;
    __syncthreads();
    float S = red[0] + red[1] + red[2] + red[3];
    float iS = 1.0f / S;
    float a[8];
    half8 h;
#pragma unroll
    for (int i = 0; i < 8; ++i) { a[i] = e[i] * iS; h[i] = (f16)a[i]; }
    *(half8*)(Wm + ((size_t)b * KSEL + k) * SEQ_ + t * 8) = h;
#pragma unroll
    for (int i = 0; i < 8; ++i) c[i] += logf(fmaxf(1.0f - a[i], 1e-6f));
    __syncthreads();
  }
}

// ---- GZ (split-K=2): Zpart[b][kc] = Wm[b][:, kc*1024:+1024] @ xproj-part. grid (4, 2, 32)
__global__ __launch_bounds__(256) void gz_kernel(const f16* __restrict__ Wm,
    const f16* __restrict__ xprojT, float* __restrict__ Zpart) {
  GEMM_PROLOG
  int b = blockIdx.z, kc = blockIdx.y;
  int n0 = blockIdx.x * 128;
  const f16* A = Wm + (long)b * KSEL * SEQ_;
  const f16* BT = xprojT + (long)b * 512 * SEQ_;
  float* Zb = Zpart + ((long)b * 2 + kc) * KSEL * 512;
  int kbeg = kc * 1024, kend = kbeg + 1024;
  for (int k0 = kbeg; k0 < kend; k0 += 32) {
    stage_gll(A, SEQ_, 0, k0, As, t);
    stage_gll(BT, SEQ_, n0, k0, Bs, t);
    __syncthreads();
    mfma_step(As, Bs, lane, wr, wc, acc);
    __syncthreads();
  }
#pragma unroll
  for (int mi = 0; mi < 4; ++mi)
#pragma unroll
    for (int ni = 0; ni < 4; ++ni) {
      int c = n0 + wc * 64 + ni * 16 + (lane & 15);
      int r0 = wr * 64 + mi * 16 + (lane >> 4) * 4;
#pragma unroll
      for (int j = 0; j < 4; ++j)
        Zb[(long)(r0 + j) * 512 + c] = acc[mi][ni][j];
    }
}

// ---- reduce split-K parts + transpose -> ZT[b][512][128] f16. grid (16, 4, 32)
__global__ __launch_bounds__(256) void ztrans_kernel(const float* __restrict__ Zpart,
                                                     f16* __restrict__ ZT) {
  __shared__ float tile[32][33];
  int b = blockIdx.z;
  int c0 = blockIdx.x * 32, r0 = blockIdx.y * 32;
  int tx = threadIdx.x, ty = threadIdx.y;
  const float* p0 = Zpart + ((long)b * 2 + 0) * KSEL * 512;
  const float* p1 = Zpart + ((long)b * 2 + 1) * KSEL * 512;
#pragma unroll
  for (int i = 0; i < 4; ++i) {
    int r = r0 + ty + i * 8, c = c0 + tx;
    tile[ty + i * 8][tx] = p0[(long)r * 512 + c] + p1[(long)r * 512 + c];
  }
  __syncthreads();
  f16* d = ZT + (long)b * 512 * KSEL;
#pragma unroll
  for (int i = 0; i < 4; ++i) {
    int c = c0 + ty + i * 8, r = r0 + tx;
    d[(long)c * KSEL + r] = (f16)tile[tx][ty + i * 8];
  }
}

// ---- GY: rbuf = xproj + Wm^T @ Z. grid (4, 16, 32)
__global__ __launch_bounds__(256) void gy_kernel(const f16* __restrict__ WmT,
    const f16* __restrict__ ZT, const f16* __restrict__ xproj,
    f16* __restrict__ rbuf) {
  GEMM_PROLOG
  int b = blockIdx.z;
  int m0 = blockIdx.y * 128, n0 = blockIdx.x * 128;
  const f16* A = WmT + (long)b * SEQ_ * KSEL;
  const f16* BT = ZT + (long)b * 512 * KSEL;
  const f16* xpb = xproj + (long)b * SEQ_ * 512;
  f16* rb = rbuf + (long)b * SEQ_ * 512;
  for (int k0 = 0; k0 < KSEL; k0 += 32) {
    stage_gll(A, KSEL, m0, k0, As, t);
    stage_gll(BT, KSEL, n0, k0, Bs, t);
    __syncthreads();
    mfma_step(As, Bs, lane, wr, wc, acc);
    __syncthreads();
  }
#pragma unroll
  for (int mi = 0; mi < 4; ++mi)
#pragma unroll
    for (int ni = 0; ni < 4; ++ni) {
      int c = n0 + wc * 64 + ni * 16 + (lane & 15);
      int r0 = m0 + wr * 64 + mi * 16 + (lane >> 4) * 4;
#pragma unroll
      for (int j = 0; j < 4; ++j) {
        long idx = (long)(r0 + j) * 512 + c;
        rb[idx] = (f16)((float)xpb[idx] + acc[mi][ni][j]);
      }
    }
}

// ---- G4: out = ln4(rbuf)@W4 + b4 (fp32 out). grid (4, 512)
__global__ __launch_bounds__(256) void g4_kernel(const f16* __restrict__ rbuf,
    const float* __restrict__ mean, const float* __restrict__ rstd,
    const float* __restrict__ g4, const float* __restrict__ bl4,
    const f16* __restrict__ W4T, const float* __restrict__ b4,
    float* __restrict__ out) {
  GEMM_PROLOG
  int m0 = blockIdx.y * 128, n0 = blockIdx.x * 128;
  for (int k0 = 0; k0 < 512; k0 += 32) {
    stage_a_ln_f16(rbuf, 512, mean, rstd, g4, bl4, m0, k0, As, t);
    stage_gll(W4T, 512, n0, k0, Bs, t);
    __syncthreads();
    mfma_step(As, Bs, lane, wr, wc, acc);
    __syncthreads();
  }
#pragma unroll
  for (int mi = 0; mi < 4; ++mi)
#pragma unroll
    for (int ni = 0; ni < 4; ++ni) {
      int c = n0 + wc * 64 + ni * 16 + (lane & 15);
      float bias = b4[c];
      int r0 = m0 + wr * 64 + mi * 16 + (lane >> 4) * 4;
#pragma unroll
      for (int j = 0; j < 4; ++j)
        out[(long)(r0 + j) * 512 + c] = acc[mi][ni][j] + bias;
    }
}

// ======================= launcher =======================
extern "C" void kernel_launch(void* const* d_in, const int* in_sizes, int n_in,
                              void* d_out, int out_size, void* d_ws, size_t ws_size,
                              hipStream_t stream) {
  const float* x    = (const float*)d_in[0];
  const float* tau  = (const float*)d_in[1];
  const float* g1   = (const float*)d_in[2];
  const float* bl1  = (const float*)d_in[3];
  const float* W1   = (const float*)d_in[4];
  const float* b1   = (const float*)d_in[5];
  const float* g2   = (const float*)d_in[6];
  const float* bl2  = (const float*)d_in[7];
  const float* W2   = (const float*)d_in[8];
  const float* b2   = (const float*)d_in[9];
  const float* g3   = (const float*)d_in[10];
  const float* bl3  = (const float*)d_in[11];
  const float* W3   = (const float*)d_in[12];
  const float* b3   = (const float*)d_in[13];
  const float* g4   = (const float*)d_in[14];
  const float* bl4  = (const float*)d_in[15];
  const float* W4   = (const float*)d_in[16];
  const float* b4   = (const float*)d_in[17];
  float* out = (float*)d_out;

  const long NTOK = (long)B_ * SEQ_;  // 65536

  // ---- workspace layout ----
  char* ws = (char*)d_ws;
  f16* regA   = (f16*)(ws);                         // 64MB: A2, later xproj
  f16* regB   = (f16*)(ws + (64l << 20));           // 64MB: xsum, later rbuf
  float* Zpart = (float*)(ws + (128l << 20));       // 16MB (split-K=2 fp32)
  f16* W2T    = (f16*)(ws + (144l << 20));          // 8MB
  f16* W1T    = (f16*)(ws + (152l << 20));          // 0.5MB
  f16* W3T    = (f16*)(ws + (153l << 20));          // 0.51MB
  f16* W4T    = (f16*)(ws + (154l << 20));          // 0.5MB
  float* xscore = (float*)(ws + (155l << 20));      // 0.25MB
  float* meanA  = (float*)(ws + (156l << 20));      // 0.25MB
  float* rstdA  = meanA + NTOK;                     // 0.25MB
  float* mean2  = rstdA + NTOK;                     // 64KB
  float* rstd2  = mean2 + B_ * 512;                 // 64KB
  float2* part  = (float2*)(rstd2 + B_ * 512);      // 1MB (dead after colstats_fin)

  // ---- d_out (128MB) doubles as scratch, fully overwritten by G4 ----
  // SIZES: xtok 64MB; xprojT 64MB (reuses xtok region AFTER g3);
  //        Wm f16 16MB; WmT f16 16MB; ZT f16 4MB. No overlaps live at once.
  f16* xtok   = (f16*)d_out;                               // [0,64) until g2 reads it
  f16* xprojT = (f16*)d_out;                               // [0,64) written step 5 (xtok dead)
  f16* Wm     = (f16*)((char*)d_out + (64l << 20));        // [64,80)
  f16* WmT    = (f16*)((char*)d_out + (80l << 20));        // [80,96)
  f16* ZT     = (f16*)((char*)d_out + (96l << 20));        // [96,100)

  f16* A2    = regA;
  f16* xsum  = regB;
  f16* xproj = regA;   // A2 dead after G2
  f16* rbuf  = regB;   // xsum dead after G3

  dim3 tb(32, 8);

  // weight transposes (f16, [n][k])
  transpose_cvt<float><<<dim3(16, 16, 1), tb, 0, stream>>>(W1, W1T, 512, 512, 0, 0);
  transpose_cvt<float><<<dim3(64, 64, 1), tb, 0, stream>>>(W2, W2T, 2048, 2048, 0, 0);
  transpose_cvt<float><<<dim3(17, 16, 1), tb, 0, stream>>>(W3, W3T, 512, 513, 0, 0);
  transpose_cvt<float><<<dim3(16, 16, 1), tb, 0, stream>>>(W4, W4T, 512, 512, 0, 0);

  // 1) LN1 stats + G1 -> xtok (f16, in d_out)
  rowstats512<<<NTOK / 4, 256, 0, stream>>>(x, meanA, rstdA);
  g1_kernel<<<dim3(4, 512), 256, 0, stream>>>(x, meanA, rstdA, g1, bl1, W1T, b1, xtok);

  // 2) LN2 stats + transposed normalize -> A2, then G2 -> xsum
  colstats_part<<<B_ * 8, 512, 0, stream>>>(xtok, part);
  colstats_fin<<<64, 256, 0, stream>>>(part, mean2, rstd2);
  trans2_kernel<<<dim3(16, 64, B_), tb, 0, stream>>>(xtok, mean2, rstd2, g2, bl2, A2);
  g2_kernel<<<dim3(4, 16, B_), 256, 0, stream>>>(W2T, A2, b2, xtok, xsum);

  // 3) LN3 stats, score column, G3 -> xproj (overwrites A2; xtok now dead)
  rowstats512_f16<<<NTOK / 4, 256, 0, stream>>>(xsum, meanA, rstdA);
  score_kernel<<<NTOK / 4, 256, 0, stream>>>(xsum, meanA, rstdA, g3, bl3, W3T, b3, xscore);
  g3_kernel<<<dim3(4, 512), 256, 0, stream>>>(xsum, meanA, rstdA, g3, bl3, W3T + 512, b3, xproj);

  // 4) top-k -> Wm (f16, d_out[64,80))
  topk_kernel<<<B_, 256, 0, stream>>>(xscore, tau, Wm);

  // 5) transposes for GZ/GY operands (xprojT overwrites dead xtok region)
  transpose_cvt<f16><<<dim3(16, 64, B_), tb, 0, stream>>>(xproj, xprojT, 2048, 512,
      (long)SEQ_ * 512, (long)512 * SEQ_);
  transpose_cvt<f16><<<dim3(64, 4, B_), tb, 0, stream>>>(Wm, WmT, 128, 2048,
      (long)KSEL * SEQ_, (long)SEQ_ * KSEL);

  // 6) Z = Wm @ xproj (split-K=2), then reduce+transpose -> ZT
  gz_kernel<<<dim3(4, 2, B_), 256, 0, stream>>>(Wm, xprojT, Zpart);
  ztrans_kernel<<<dim3(16, 4, B_), tb, 0, stream>>>(Zpart, ZT);

  // 7) rbuf = xproj + Wm^T @ Z (overwrites xsum)
  gy_kernel<<<dim3(4, 16, B_), 256, 0, stream>>>(WmT, ZT, xproj, rbuf);

  // 8) LN4 stats + G4 -> out (overwrites all d_out scratch)
  rowstats512_f16<<<NTOK / 4, 256, 0, stream>>>(rbuf, meanA, rstdA);
  g4_kernel<<<dim3(4, 512), 256, 0, stream>>>(rbuf, meanA, rstdA, g4, bl4, W4T, b4, out);
}